// Round 3
// baseline (511.560 us; speedup 1.0000x reference)
//
#include <hip/hip_runtime.h>
#include <hip/hip_bf16.h>

// Problem constants (fixed by setup_inputs)
constexpr int TDIM = 16384;
constexpr int DIN  = 4096;
constexpr int DOUT = 4096;
constexpr int RNK  = 32;
constexpr float EPSF = 1e-8f;

using i32x4 = __attribute__((ext_vector_type(4))) int;

// ---------------------------------------------------------------------------
// Kernel 1: weight_eff = W + loraB @ loraA  -> per-row absmax -> int8 quantize
// (unchanged from round 2)
// ---------------------------------------------------------------------------
__global__ __launch_bounds__(256)
void wquant_kernel(const float* __restrict__ W,
                   const float* __restrict__ Amat,   // [32, 4096]
                   const float* __restrict__ Bmat,   // [4096, 32]
                   float* __restrict__ a_w,          // [4096]
                   signed char* __restrict__ qw)     // [4096, 4096]
{
    const int tid = threadIdx.x;
    const int o0  = blockIdx.x * 4;

    __shared__ float Bsh[4][32];
    __shared__ float red[4][4];
    __shared__ float awsh[4];

    if (tid < 128) {
        int r = tid >> 5, c = tid & 31;
        Bsh[r][c] = Bmat[(size_t)(o0 + r) * RNK + c];
    }
    __syncthreads();

    float4 acc[4][4];
    #pragma unroll
    for (int r = 0; r < 4; ++r)
        #pragma unroll
        for (int c = 0; c < 4; ++c)
            acc[r][c] = *(const float4*)(W + (size_t)(o0 + r) * DIN + c * 1024 + tid * 4);

    #pragma unroll 4
    for (int k = 0; k < RNK; ++k) {
        float4 a[4];
        #pragma unroll
        for (int c = 0; c < 4; ++c)
            a[c] = *(const float4*)(Amat + (size_t)k * DIN + c * 1024 + tid * 4);
        #pragma unroll
        for (int r = 0; r < 4; ++r) {
            const float b = Bsh[r][k];
            #pragma unroll
            for (int c = 0; c < 4; ++c) {
                acc[r][c].x += b * a[c].x; acc[r][c].y += b * a[c].y;
                acc[r][c].z += b * a[c].z; acc[r][c].w += b * a[c].w;
            }
        }
    }

    const int wid = tid >> 6;
    #pragma unroll
    for (int r = 0; r < 4; ++r) {
        float m = 0.f;
        #pragma unroll
        for (int c = 0; c < 4; ++c) {
            float4 v = acc[r][c];
            m = fmaxf(m, fmaxf(fmaxf(fabsf(v.x), fabsf(v.y)),
                               fmaxf(fabsf(v.z), fabsf(v.w))));
        }
        for (int off = 1; off < 64; off <<= 1)
            m = fmaxf(m, __shfl_xor(m, off));
        if ((tid & 63) == 0) red[wid][r] = m;
    }
    __syncthreads();
    if (tid < 4) {
        float m = fmaxf(fmaxf(red[0][tid], red[1][tid]),
                        fmaxf(red[2][tid], red[3][tid]));
        float aw = m + EPSF;
        awsh[tid] = aw;
        a_w[o0 + tid] = aw;
    }
    __syncthreads();

    #pragma unroll
    for (int r = 0; r < 4; ++r) {
        const float aw = awsh[r];
        #pragma unroll
        for (int c = 0; c < 4; ++c) {
            float4 v = acc[r][c];
            int q0 = __float2int_rn((v.x / aw) * 127.0f);
            int q1 = __float2int_rn((v.y / aw) * 127.0f);
            int q2 = __float2int_rn((v.z / aw) * 127.0f);
            int q3 = __float2int_rn((v.w / aw) * 127.0f);
            unsigned int packed = (q0 & 0xff) | ((q1 & 0xff) << 8) |
                                  ((q2 & 0xff) << 16) | ((q3 & 0xff) << 24);
            *(unsigned int*)(qw + (size_t)(o0 + r) * DIN + c * 1024 + tid * 4) = packed;
        }
    }
}

// ---------------------------------------------------------------------------
// Kernel 2: x quantize (unchanged from round 2 — coalesced)
// ---------------------------------------------------------------------------
__global__ __launch_bounds__(256)
void xquant_kernel(const float* __restrict__ x,
                   const float* __restrict__ axp,
                   unsigned int* __restrict__ qx)
{
    const float inv = 1.0f / fmaxf(axp[0], EPSF);
    const size_t base = (size_t)blockIdx.x * 1024 + threadIdx.x;
    const float4* xv = (const float4*)x;

    float4 v[4];
    #pragma unroll
    for (int j = 0; j < 4; ++j)
        v[j] = xv[base + j * 256];

    #pragma unroll
    for (int j = 0; j < 4; ++j) {
        int q0 = __float2int_rn(fminf(fmaxf(v[j].x * inv, -1.f), 1.f) * 127.0f);
        int q1 = __float2int_rn(fminf(fmaxf(v[j].y * inv, -1.f), 1.f) * 127.0f);
        int q2 = __float2int_rn(fminf(fmaxf(v[j].z * inv, -1.f), 1.f) * 127.0f);
        int q3 = __float2int_rn(fminf(fmaxf(v[j].w * inv, -1.f), 1.f) * 127.0f);
        qx[base + j * 256] = (q0 & 0xff) | ((q1 & 0xff) << 8) |
                             ((q2 & 0xff) << 16) | ((q3 & 0xff) << 24);
    }
}

// ---------------------------------------------------------------------------
// Kernel 3: int8 GEMM — 8-phase 256x256 template (T2+T3+T4+T5).
// 512 thr = 8 waves (2M x 4N), wave tile 128x64, 16x16x64 i8 MFMA (proven
// layout from rounds 1-2). BK=64B, 3 LDS buffers (96KB), prefetch distance 2,
// counted vmcnt(4) once per K-tile (never 0 in loop). 2 phases/K-tile,
// 16 MFMA per phase wrapped in setprio. LDS swizzle: 16B-block key=(row>>1)&3
// (2-way = free); applied via inverse-swizzled GLOBAL src + swizzled ds_read,
// linear global_load_lds dest (rule #21).
// ---------------------------------------------------------------------------
__global__ __launch_bounds__(512, 2)
void gemm_i8_kernel(const signed char* __restrict__ qx,   // [16384, 4096]
                    const signed char* __restrict__ qw,   // [4096, 4096]
                    const float* __restrict__ a_w,        // [4096]
                    const float* __restrict__ bias,       // [4096]
                    const float* __restrict__ axp,
                    float* __restrict__ out)              // [16384, 4096]
{
    __shared__ signed char As[3][256 * 64];   // 48 KB
    __shared__ signed char Bs[3][256 * 64];   // 48 KB

    const int tid  = threadIdx.x;
    const int lane = tid & 63;
    const int wid  = tid >> 6;     // 0..7
    const int wm   = wid >> 2;     // 0..1 (M half)
    const int wn   = wid & 3;      // 0..3 (N quarter)

    const int bid = blockIdx.x;
    const int nb  = bid & 15;      // N fastest: 16 consecutive blocks share qx panel
    const int mb  = bid >> 4;

    const size_t K = DIN;
    constexpr int NT = DIN / 64;   // 64 K-tiles

    // ---- staging addressing: 512 thr x 16B = 8KB/pass, 2 passes per operand tile
    const int srow = tid >> 2;                       // 0..127 (pass j adds 128)
    const int skb  = ((tid & 3) ^ ((srow >> 1) & 3)) << 4;  // inverse-swizzled src block
    const signed char* aPanel = qx + (size_t)(mb * 256) * K;
    const signed char* bPanel = qw + (size_t)(nb * 256) * K;

    // ---- fragment read addressing (16x16x64: row=lane&15, K-block=lane>>4) ----
    const int r15  = lane & 15;
    const int blk  = lane >> 4;
    const int rkey = (r15 >> 1) & 3;                 // invariant across m/n (stride 16 rows)
    const int rblk = (blk ^ rkey) << 4;
    const int aRd  = (wm * 128 + r15) * 64 + rblk;   // + m*1024
    const int bRd  = (wn * 64 + r15) * 64 + rblk;    // + n*1024

    i32x4 acc[8][4];
    #pragma unroll
    for (int m = 0; m < 8; ++m)
        #pragma unroll
        for (int n = 0; n < 4; ++n) acc[m][n] = i32x4{0, 0, 0, 0};

    // stage helpers: 2 x global_load_lds (16B) for one operand K-tile
#define STAGE(panel, ldsbuf, tt)                                               \
    {                                                                          \
        const int tc = (tt) < NT ? (tt) : (NT - 1);                            \
        const size_t kOff = (size_t)tc * 64;                                   \
        _Pragma("unroll")                                                      \
        for (int j = 0; j < 2; ++j) {                                          \
            const int row = j * 128 + srow;                                    \
            __builtin_amdgcn_global_load_lds(                                  \
                (const __attribute__((address_space(1))) unsigned int*)        \
                    ((panel) + (size_t)row * K + kOff + skb),                  \
                (__attribute__((address_space(3))) unsigned int*)              \
                    ((ldsbuf) + j * 8192 + tid * 16),                          \
                16, 0, 0);                                                     \
        }                                                                      \
    }

    // ---- prologue: stage tiles 0 and 1, wait tile 0 (vmcnt(4) leaves tile 1) ----
    STAGE(aPanel, As[0], 0);
    STAGE(bPanel, Bs[0], 0);
    STAGE(aPanel, As[1], 1);
    STAGE(bPanel, Bs[1], 1);
    asm volatile("s_waitcnt vmcnt(4)" ::: "memory");
    __builtin_amdgcn_sched_barrier(0);
    __builtin_amdgcn_s_barrier();

    for (int t = 0; t < NT; ++t) {
        const int cur = t % 3;
        const int nxt = (t + 2) % 3;
        const signed char* Ab = As[cur];
        const signed char* Bb = Bs[cur];

        // ---------- phase 0: A m0-3 + all B, stage A(t+2), MFMA quadrant ----------
        i32x4 af[4], bf[4];
        #pragma unroll
        for (int m = 0; m < 4; ++m)
            af[m] = *(const i32x4*)(Ab + aRd + m * 1024);
        #pragma unroll
        for (int n = 0; n < 4; ++n)
            bf[n] = *(const i32x4*)(Bb + bRd + n * 1024);
        STAGE(aPanel, As[nxt], t + 2);
        __builtin_amdgcn_s_barrier();
        asm volatile("s_waitcnt lgkmcnt(0)" ::: "memory");
        __builtin_amdgcn_sched_barrier(0);
        __builtin_amdgcn_s_setprio(1);
        #pragma unroll
        for (int m = 0; m < 4; ++m)
            #pragma unroll
            for (int n = 0; n < 4; ++n)
                acc[m][n] = __builtin_amdgcn_mfma_i32_16x16x64_i8(
                    af[m], bf[n], acc[m][n], 0, 0, 0);
        __builtin_amdgcn_s_setprio(0);
        __builtin_amdgcn_sched_barrier(0);
        __builtin_amdgcn_s_barrier();

        // ---------- phase 1: A m4-7 (B reused in regs), stage B(t+2), MFMA ----------
        i32x4 ag[4];
        #pragma unroll
        for (int m = 0; m < 4; ++m)
            ag[m] = *(const i32x4*)(Ab + aRd + (m + 4) * 1024);
        STAGE(bPanel, Bs[nxt], t + 2);
        __builtin_amdgcn_s_barrier();
        asm volatile("s_waitcnt lgkmcnt(0)" ::: "memory");
        __builtin_amdgcn_sched_barrier(0);
        __builtin_amdgcn_s_setprio(1);
        #pragma unroll
        for (int m = 0; m < 4; ++m)
            #pragma unroll
            for (int n = 0; n < 4; ++n)
                acc[m + 4][n] = __builtin_amdgcn_mfma_i32_16x16x64_i8(
                    ag[m], bf[n], acc[m + 4][n], 0, 0, 0);
        __builtin_amdgcn_s_setprio(0);
        __builtin_amdgcn_sched_barrier(0);
        // counted vmcnt ONCE per K-tile: allow the 4 loads for t+2, require t+1 done
        asm volatile("s_waitcnt vmcnt(4)" ::: "memory");
        __builtin_amdgcn_sched_barrier(0);
        __builtin_amdgcn_s_barrier();
    }
#undef STAGE

    // ---- epilogue: C/D layout col=lane&15, row=(lane>>4)*4+reg ----
    const float ax = fmaxf(axp[0], EPSF);
    #pragma unroll
    for (int n = 0; n < 4; ++n) {
        const int o = nb * 256 + wn * 64 + n * 16 + r15;
        const float scale = ax * a_w[o] * (1.0f / 16129.0f);
        const float bs = bias[o];
        #pragma unroll
        for (int m = 0; m < 8; ++m) {
            const int t0 = mb * 256 + wm * 128 + m * 16 + (blk << 2);
            float* op = out + (size_t)t0 * DOUT + o;
            #pragma unroll
            for (int r = 0; r < 4; ++r)
                op[(size_t)r * DOUT] = (float)acc[m][n][r] * scale + bs;
        }
    }
}

// ---------------------------------------------------------------------------
extern "C" void kernel_launch(void* const* d_in, const int* in_sizes, int n_in,
                              void* d_out, int out_size, void* d_ws, size_t ws_size,
                              hipStream_t stream)
{
    const float* x    = (const float*)d_in[0];
    const float* W    = (const float*)d_in[1];
    const float* lA   = (const float*)d_in[2];
    const float* lB   = (const float*)d_in[3];
    const float* bias = (const float*)d_in[4];
    const float* ax   = (const float*)d_in[5];
    float* out        = (float*)d_out;

    // workspace: qx (64MB) | qw (16MB) | a_w (16KB)
    signed char* qx = (signed char*)d_ws;
    signed char* qw = qx + (size_t)TDIM * DIN;
    float* a_w      = (float*)(qw + (size_t)DOUT * DIN);

    wquant_kernel<<<DOUT / 4, 256, 0, stream>>>(W, lA, lB, a_w, qw);

    const int xblocks = (int)(((size_t)TDIM * DIN) / (16 * 256));  // 16384
    xquant_kernel<<<xblocks, 256, 0, stream>>>(x, ax, (unsigned int*)qx);

    gemm_i8_kernel<<<(TDIM / 256) * (DOUT / 256), 512, 0, stream>>>(
        qx, qw, a_w, bias, ax, out);
}